// Round 7
// baseline (262.678 us; speedup 1.0000x reference)
//
#include <hip/hip_runtime.h>
#include <hip/hip_bf16.h>

// MHA forward: B=4, C=2048, E=1024, H=16, D=64.
// bf16 MFMA 16x16x32, fp32 accumulation. Verified gfx950 layouts:
//   A-frag: A[m=lane&15][k=quad*8+j]; B-frag: B[k=quad*8+j][n=lane&15]
//   C/D   : col=lane&15, row=quad*4+reg
// R6: attn back to 8-wave/128-q blocks (R5's 64-q halved arithmetic
//     intensity per staged byte -> regression). Residency via LPT:
//     1024 unpaired blocks, longest (qt=15) dispatched first, 4 blocks/CU
//     by LDS. Raw v_exp_f32 instead of ocml exp2.

typedef __attribute__((ext_vector_type(8))) short short8;
typedef __attribute__((ext_vector_type(4))) float floatx4;
typedef __attribute__((ext_vector_type(4))) unsigned short ushort4v;

__device__ __forceinline__ unsigned short f2bf(float f) {
    __hip_bfloat16 h = __float2bfloat16(f);
    return __builtin_bit_cast(unsigned short, h);
}

// async 16B global -> LDS (LDS dest = wave-uniform base + lane*16)
__device__ __forceinline__ void gl2lds16(const unsigned short* g, unsigned short* l) {
    __builtin_amdgcn_global_load_lds(
        (const __attribute__((address_space(1))) unsigned int*)g,
        (__attribute__((address_space(3))) unsigned int*)l, 16, 0, 0);
}

// ---- fused prep: x fp32->bf16 (blocks 0..8191) + 4 weight transposes ----
// (blocks 8192..9215). z=0 (W_q) scaled by 0.125*log2e.
__global__ __launch_bounds__(256) void prep_kernel(const float* __restrict__ x,
                                                   const float* __restrict__ W0,
                                                   const float* __restrict__ W1,
                                                   const float* __restrict__ W2,
                                                   const float* __restrict__ W3,
                                                   unsigned short* __restrict__ xb,
                                                   unsigned short* __restrict__ wt) {
    __shared__ float tile[64][65];
    const int id = blockIdx.x;
    if (id < 8192) {
        const int i = id * 256 + threadIdx.x;
        const float4 v = ((const float4*)x)[i];
        ushort4v o;
        o[0] = f2bf(v.x); o[1] = f2bf(v.y); o[2] = f2bf(v.z); o[3] = f2bf(v.w);
        ((ushort4v*)xb)[i] = o;
        return;
    }
    const int t2 = id - 8192;
    const int z = t2 >> 8;
    const float* src = (z == 0) ? W0 : (z == 1) ? W1 : (z == 2) ? W2 : W3;
    const float scale = (z == 0) ? 0.18033688011112042f : 1.0f;  // 0.125*log2e
    unsigned short* dst = wt + (size_t)z * 1048576;
    const int k0 = ((t2 >> 4) & 15) * 64, n0 = (t2 & 15) * 64;
    const int t = threadIdx.x;
    const int r = t >> 4, c4 = (t & 15) * 4;
    #pragma unroll
    for (int p = 0; p < 4; ++p) {
        const int kk = p * 16 + r;
        const float4 v = *(const float4*)&src[(size_t)(k0 + kk) * 1024 + n0 + c4];
        tile[kk][c4 + 0] = v.x; tile[kk][c4 + 1] = v.y;
        tile[kk][c4 + 2] = v.z; tile[kk][c4 + 3] = v.w;
    }
    __syncthreads();
    #pragma unroll
    for (int p = 0; p < 4; ++p) {
        const int nn = p * 16 + r;
        ushort4v o;
        #pragma unroll
        for (int j = 0; j < 4; ++j) o[j] = f2bf(tile[c4 + j][nn] * scale);
        *(ushort4v*)&dst[(size_t)(n0 + nn) * 1024 + k0 + c4] = o;
    }
}

// ---------------- 128x128-tile bf16 MFMA GEMM, BK=64, M=8192, K=1024 ------
// MODE 0: A = x bf16, Bt = WqkvT (3072 x 1024): one dispatch computes Q,K,V.
//         Q,K -> (B,H,C,D) bf16; V -> (B,H,D,C) bf16 (transposed).
// MODE 1: Bt = WoT (1024 x 1024), fp32 output row-major.
// 1D grid; id&7 = XCD slot owns m-slice [8*(id&7), 8*(id&7)+8).
template<int MODE, int NBLK>
__global__ __launch_bounds__(256) void gemm128(const unsigned short* __restrict__ A,
                                               const unsigned short* __restrict__ Bt,
                                               unsigned short* __restrict__ obf,
                                               float* __restrict__ ofp) {
    constexpr int Kd = 1024;
    __shared__ __align__(16) unsigned short Al[128 * 64];
    __shared__ __align__(16) unsigned short Bl[128 * 64];
    const int id = blockIdx.x;
    const int xcd = id & 7;
    const int q = id >> 3;
    const int m_blk = xcd * 8 + (q & 7);   // m-slice per XCD: A set = 2 MB
    const int n_blk = q >> 3;              // n varies slowest
    const int m0 = m_blk * 128, n0 = n_blk * 128;

    const int tid = threadIdx.x;
    const int lane = tid & 63, w = tid >> 6;
    const int quad = lane >> 4, l15 = lane & 15;
    const int wm = (w & 1) * 64, wn = (w >> 1) * 64;
    const int srow = lane >> 3, sc = lane & 7;
    const int gc = (sc ^ srow) * 8;        // swizzled source chunk

    floatx4 acc[4][4];
    #pragma unroll
    for (int i = 0; i < 4; ++i)
        #pragma unroll
        for (int j = 0; j < 4; ++j) acc[i][j] = (floatx4){0.f, 0.f, 0.f, 0.f};

    for (int kt = 0; kt < Kd / 64; ++kt) {
        const int k0 = kt * 64;
        #pragma unroll
        for (int p = 0; p < 4; ++p) {
            const int row0 = w * 32 + p * 8;
            gl2lds16(&A[(size_t)(m0 + row0 + srow) * Kd + k0 + gc], &Al[row0 * 64]);
            gl2lds16(&Bt[(size_t)(n0 + row0 + srow) * Kd + k0 + gc], &Bl[row0 * 64]);
        }
        __syncthreads();
        #pragma unroll
        for (int kk = 0; kk < 2; ++kk) {
            short8 af[4], bfv[4];
            #pragma unroll
            for (int i = 0; i < 4; ++i) {
                const int row = wm + i * 16 + l15;
                af[i] = *(const short8*)&Al[row * 64 + ((kk * 4 + quad) ^ (row & 7)) * 8];
            }
            #pragma unroll
            for (int i = 0; i < 4; ++i) {
                const int row = wn + i * 16 + l15;
                bfv[i] = *(const short8*)&Bl[row * 64 + ((kk * 4 + quad) ^ (row & 7)) * 8];
            }
            #pragma unroll
            for (int i = 0; i < 4; ++i)
                #pragma unroll
                for (int j = 0; j < 4; ++j)
                    acc[i][j] = __builtin_amdgcn_mfma_f32_16x16x32_bf16(
                        af[i], bfv[j], acc[i][j], 0, 0, 0);
        }
        __syncthreads();
    }

    #pragma unroll
    for (int i = 0; i < 4; ++i) {
        if (MODE == 0 && n0 >= 2048) {
            #pragma unroll
            for (int j = 0; j < 4; ++j) {        // V^T: pack 4 consecutive c
                const int mb = m0 + wm + i * 16 + quad * 4;
                const int n = n0 + wn + j * 16 + l15;
                const int b = mb >> 11, c0 = mb & 2047;
                const int nl = n & 1023, hh = nl >> 6, d = nl & 63;
                ushort4v pv;
                #pragma unroll
                for (int r = 0; r < 4; ++r) pv[r] = f2bf(acc[i][j][r]);
                *(ushort4v*)&obf[16777216 + ((size_t)(b * 16 + hh) * 64 + d) * 2048 + c0] = pv;
            }
        } else {
            #pragma unroll
            for (int r = 0; r < 4; ++r) {
                const int m = m0 + wm + i * 16 + quad * 4 + r;
                #pragma unroll
                for (int j = 0; j < 4; ++j) {
                    const int n = n0 + wn + j * 16 + l15;
                    const float v = acc[i][j][r];
                    if (MODE == 0) {   // Q,K: (B,H,C,D), z = n>>10
                        const int b = m >> 11, c = m & 2047;
                        const int z = n >> 10, nl = n & 1023, hh = nl >> 6, d = nl & 63;
                        obf[(size_t)z * 8388608 +
                            ((size_t)(b * 16 + hh) * 2048 + c) * 64 + d] = f2bf(v);
                    } else {
                        ofp[(size_t)m * 1024 + n] = v;
                    }
                }
            }
        }
    }
}

// ---------------- causal flash attention (transposed-S, LPT grid) ---------
// Q(pre-scaled),K: (B,H,C,D) bf16; Vt: (B,H,D,C) bf16; Hid: (B,C,H*D) bf16.
// 512 thr = 8 waves, 16 q/wave -> 128 q per block; one q-tile per block.
// 1024 blocks, qt = 15 - ((id>>3)&15): longest blocks dispatch first (LPT).
// id&7 = bh&7 -> all q-blocks of a head on one XCD. 4 blocks/CU by LDS.
__global__ __launch_bounds__(512, 8) void attn_kernel(const unsigned short* __restrict__ Q,
                                                      const unsigned short* __restrict__ K,
                                                      const unsigned short* __restrict__ Vt,
                                                      unsigned short* __restrict__ Hid) {
    __shared__ __align__(16) unsigned short Kl[64 * 64];    // [key][d], swizzled
    __shared__ __align__(16) unsigned short Vl[64 * 64];    // [d][key], swizzled
    __shared__ __align__(16) unsigned short Pl[8][16 * 72]; // per-wave [q][k]
    const int id = blockIdx.x;
    const int bh = (id >> 7) * 8 + (id & 7);   // all qt of bh share id&7 (XCD)
    const int qt = 15 - ((id >> 3) & 15);      // LPT: long blocks first
    const int b = bh >> 4, h = bh & 15;
    const int tid = threadIdx.x, w = tid >> 6, lane = tid & 63;
    const int quad = lane >> 4, l15 = lane & 15;
    const int sw = quad ^ (l15 & 7);
    const int srow = lane >> 3, sc = lane & 7;
    const int g8 = (sc ^ srow) * 8;            // staging source swizzle
    const size_t bhs = (size_t)(b * 16 + h) * 2048 * 64;
    const unsigned short* Qb = Q + bhs;
    const unsigned short* Kb = K + bhs;
    const unsigned short* Vb = Vt + bhs;       // (D=64) x (C=2048)

    const int q0 = qt * 128;
    const int qw = q0 + w * 16;
    const int myq = qw + l15;
    const short8 bq0 = *(const short8*)&Qb[(size_t)myq * 64 + quad * 8];
    const short8 bq1 = *(const short8*)&Qb[(size_t)myq * 64 + 32 + quad * 8];

    floatx4 o[4];
    #pragma unroll
    for (int i = 0; i < 4; ++i) o[i] = (floatx4){0.f, 0.f, 0.f, 0.f};
    float li = 0.f;

    const int nT = (q0 + 128) >> 6;
    for (int t = 0; t < nT; ++t) {
        const int k0 = t * 64;
        {   // stage K [64key x 64d] and V^T [64d x 64key], swizzled source
            const int krow = w * 8 + srow;
            gl2lds16(&Kb[(size_t)(k0 + krow) * 64 + g8], &Kl[w * 512]);
            gl2lds16(&Vb[(size_t)krow * 2048 + k0 + g8], &Vl[w * 512]);
        }
        __syncthreads();
        if (k0 <= qw + 15) {
            // ---- S^T = K * Q^T (Q pre-scaled by 0.125*log2e) ----
            floatx4 s[4];
            #pragma unroll
            for (int kf = 0; kf < 4; ++kf) {
                const int row = kf * 16 + l15;
                const short8 ka0 = *(const short8*)&Kl[row * 64 + sw * 8];
                const short8 ka1 = *(const short8*)&Kl[row * 64 + (sw ^ 4) * 8];
                floatx4 ss = (floatx4){0.f, 0.f, 0.f, 0.f};
                ss = __builtin_amdgcn_mfma_f32_16x16x32_bf16(ka0, bq0, ss, 0, 0, 0);
                ss = __builtin_amdgcn_mfma_f32_16x16x32_bf16(ka1, bq1, ss, 0, 0, 0);
                s[kf] = ss;
            }
            // ---- p = exp2(s) (raw v_exp_f32), mask only diagonal tile ----
            if (k0 + 63 > qw) {
                #pragma unroll
                for (int kf = 0; kf < 4; ++kf) {
                    ushort4v pw;
                    #pragma unroll
                    for (int r = 0; r < 4; ++r) {
                        const int key = k0 + kf * 16 + quad * 4 + r;
                        const float p = (key > myq) ? 0.f
                                        : __builtin_amdgcn_exp2f(s[kf][r]);
                        li += p;
                        pw[r] = f2bf(p);
                    }
                    *(ushort4v*)&Pl[w][l15 * 72 + kf * 16 + quad * 4] = pw;
                }
            } else {
                #pragma unroll
                for (int kf = 0; kf < 4; ++kf) {
                    ushort4v pw;
                    #pragma unroll
                    for (int r = 0; r < 4; ++r) {
                        const float p = __builtin_amdgcn_exp2f(s[kf][r]);
                        li += p;
                        pw[r] = f2bf(p);
                    }
                    *(ushort4v*)&Pl[w][l15 * 72 + kf * 16 + quad * 4] = pw;
                }
            }
            __threadfence_block();
            // ---- O^T += V^T * P^T (P-frags hoisted) ----
            const short8 pb0 = *(const short8*)&Pl[w][l15 * 72 + quad * 8];
            const short8 pb1 = *(const short8*)&Pl[w][l15 * 72 + 32 + quad * 8];
            #pragma unroll
            for (int nt = 0; nt < 4; ++nt) {
                const int row = nt * 16 + l15;
                const short8 va0 = *(const short8*)&Vl[row * 64 + sw * 8];
                const short8 va1 = *(const short8*)&Vl[row * 64 + (sw ^ 4) * 8];
                floatx4 oo = o[nt];
                oo = __builtin_amdgcn_mfma_f32_16x16x32_bf16(va0, pb0, oo, 0, 0, 0);
                oo = __builtin_amdgcn_mfma_f32_16x16x32_bf16(va1, pb1, oo, 0, 0, 0);
                o[nt] = oo;
            }
        }
        __syncthreads();
    }

    li += __shfl_xor(li, 16, 64);
    li += __shfl_xor(li, 32, 64);
    const float inv = 1.f / li;
    #pragma unroll
    for (int nt = 0; nt < 4; ++nt) {
        ushort4v ov;
        #pragma unroll
        for (int r = 0; r < 4; ++r) ov[r] = f2bf(o[nt][r] * inv);
        *(ushort4v*)&Hid[((size_t)b * 2048 + myq) * 1024 + h * 64 + nt * 16 + quad * 4] = ov;
    }
}

extern "C" void kernel_launch(void* const* d_in, const int* in_sizes, int n_in,
                              void* d_out, int out_size, void* d_ws, size_t ws_size,
                              hipStream_t stream) {
    const float* x  = (const float*)d_in[0];
    const float* Wq = (const float*)d_in[1];
    const float* Wk = (const float*)d_in[2];
    const float* Wv = (const float*)d_in[3];
    const float* Wo = (const float*)d_in[4];
    float* out = (float*)d_out;
    unsigned short* ws = (unsigned short*)d_ws;

    const size_t XB  = 0;          // x bf16:           8192x1024
    const size_t WQT = 8388608;    // WqT,WkT,WvT,WoT:  4 x 1024x1024 (N x K)
    const size_t QO  = 12582912;   // Q,K (B,H,C,D) + V (B,H,D,C): 3 x 8192x1024
    const size_t HO  = 37748736;   // hidden (B,C,H*D): 8192x1024

    prep_kernel<<<9216, 256, 0, stream>>>(x, Wq, Wk, Wv, Wo, ws + XB, ws + WQT);

    // QKV: one GEMM, N=3072 (WqT|WkT|WvT contiguous), XCD-swizzled 1D grid
    gemm128<0, 24><<<1536, 256, 0, stream>>>(ws + XB, ws + WQT, ws + QO, nullptr);
    attn_kernel<<<1024, 512, 0, stream>>>(ws + QO, ws + QO + 8388608,
                                          ws + QO + 16777216, ws + HO);
    gemm128<1, 8><<<512, 256, 0, stream>>>(ws + HO, ws + WQT + 3145728, nullptr, out);
}

// Round 8
// 232.878 us; speedup vs baseline: 1.1280x; 1.1280x over previous
//
#include <hip/hip_runtime.h>
#include <hip/hip_bf16.h>

// MHA forward: B=4, C=2048, E=1024, H=16, D=64.
// bf16 MFMA 16x16x32, fp32 accumulation. Verified gfx950 layouts:
//   A-frag: A[m=lane&15][k=quad*8+j]; B-frag: B[k=quad*8+j][n=lane&15]
//   C/D   : col=lane&15, row=quad*4+reg
// R7: attention back to paired 512-block/8-wave shape (best measured) with
//     DOUBLE-BUFFERED K/V staging: stage(t+1) issued before compute(t), so
//     the vmcnt(0)+barrier drain lands after the tile's MFMA work instead
//     of immediately after issue. One barrier per tile (was two).

typedef __attribute__((ext_vector_type(8))) short short8;
typedef __attribute__((ext_vector_type(4))) float floatx4;
typedef __attribute__((ext_vector_type(4))) unsigned short ushort4v;

__device__ __forceinline__ unsigned short f2bf(float f) {
    __hip_bfloat16 h = __float2bfloat16(f);
    return __builtin_bit_cast(unsigned short, h);
}

// async 16B global -> LDS (LDS dest = wave-uniform base + lane*16)
__device__ __forceinline__ void gl2lds16(const unsigned short* g, unsigned short* l) {
    __builtin_amdgcn_global_load_lds(
        (const __attribute__((address_space(1))) unsigned int*)g,
        (__attribute__((address_space(3))) unsigned int*)l, 16, 0, 0);
}

// ---- fused prep: x fp32->bf16 (blocks 0..8191) + 4 weight transposes ----
// (blocks 8192..9215). z=0 (W_q) scaled by 0.125*log2e.
__global__ __launch_bounds__(256) void prep_kernel(const float* __restrict__ x,
                                                   const float* __restrict__ W0,
                                                   const float* __restrict__ W1,
                                                   const float* __restrict__ W2,
                                                   const float* __restrict__ W3,
                                                   unsigned short* __restrict__ xb,
                                                   unsigned short* __restrict__ wt) {
    __shared__ float tile[64][65];
    const int id = blockIdx.x;
    if (id < 8192) {
        const int i = id * 256 + threadIdx.x;
        const float4 v = ((const float4*)x)[i];
        ushort4v o;
        o[0] = f2bf(v.x); o[1] = f2bf(v.y); o[2] = f2bf(v.z); o[3] = f2bf(v.w);
        ((ushort4v*)xb)[i] = o;
        return;
    }
    const int t2 = id - 8192;
    const int z = t2 >> 8;
    const float* src = (z == 0) ? W0 : (z == 1) ? W1 : (z == 2) ? W2 : W3;
    const float scale = (z == 0) ? 0.18033688011112042f : 1.0f;  // 0.125*log2e
    unsigned short* dst = wt + (size_t)z * 1048576;
    const int k0 = ((t2 >> 4) & 15) * 64, n0 = (t2 & 15) * 64;
    const int t = threadIdx.x;
    const int r = t >> 4, c4 = (t & 15) * 4;
    #pragma unroll
    for (int p = 0; p < 4; ++p) {
        const int kk = p * 16 + r;
        const float4 v = *(const float4*)&src[(size_t)(k0 + kk) * 1024 + n0 + c4];
        tile[kk][c4 + 0] = v.x; tile[kk][c4 + 1] = v.y;
        tile[kk][c4 + 2] = v.z; tile[kk][c4 + 3] = v.w;
    }
    __syncthreads();
    #pragma unroll
    for (int p = 0; p < 4; ++p) {
        const int nn = p * 16 + r;
        ushort4v o;
        #pragma unroll
        for (int j = 0; j < 4; ++j) o[j] = f2bf(tile[c4 + j][nn] * scale);
        *(ushort4v*)&dst[(size_t)(n0 + nn) * 1024 + k0 + c4] = o;
    }
}

// ---------------- 128x128-tile bf16 MFMA GEMM, BK=64, M=8192, K=1024 ------
// MODE 0: A = x bf16, Bt = WqkvT (3072 x 1024): one dispatch computes Q,K,V.
//         Q,K -> (B,H,C,D) bf16; V -> (B,H,D,C) bf16 (transposed).
// MODE 1: Bt = WoT (1024 x 1024), fp32 output row-major.
// 1D grid; id&7 = XCD slot owns m-slice [8*(id&7), 8*(id&7)+8).
template<int MODE, int NBLK>
__global__ __launch_bounds__(256) void gemm128(const unsigned short* __restrict__ A,
                                               const unsigned short* __restrict__ Bt,
                                               unsigned short* __restrict__ obf,
                                               float* __restrict__ ofp) {
    constexpr int Kd = 1024;
    __shared__ __align__(16) unsigned short Al[128 * 64];
    __shared__ __align__(16) unsigned short Bl[128 * 64];
    const int id = blockIdx.x;
    const int xcd = id & 7;
    const int q = id >> 3;
    const int m_blk = xcd * 8 + (q & 7);   // m-slice per XCD: A set = 2 MB
    const int n_blk = q >> 3;              // n varies slowest
    const int m0 = m_blk * 128, n0 = n_blk * 128;

    const int tid = threadIdx.x;
    const int lane = tid & 63, w = tid >> 6;
    const int quad = lane >> 4, l15 = lane & 15;
    const int wm = (w & 1) * 64, wn = (w >> 1) * 64;
    const int srow = lane >> 3, sc = lane & 7;
    const int gc = (sc ^ srow) * 8;        // swizzled source chunk

    floatx4 acc[4][4];
    #pragma unroll
    for (int i = 0; i < 4; ++i)
        #pragma unroll
        for (int j = 0; j < 4; ++j) acc[i][j] = (floatx4){0.f, 0.f, 0.f, 0.f};

    for (int kt = 0; kt < Kd / 64; ++kt) {
        const int k0 = kt * 64;
        #pragma unroll
        for (int p = 0; p < 4; ++p) {
            const int row0 = w * 32 + p * 8;
            gl2lds16(&A[(size_t)(m0 + row0 + srow) * Kd + k0 + gc], &Al[row0 * 64]);
            gl2lds16(&Bt[(size_t)(n0 + row0 + srow) * Kd + k0 + gc], &Bl[row0 * 64]);
        }
        __syncthreads();
        #pragma unroll
        for (int kk = 0; kk < 2; ++kk) {
            short8 af[4], bfv[4];
            #pragma unroll
            for (int i = 0; i < 4; ++i) {
                const int row = wm + i * 16 + l15;
                af[i] = *(const short8*)&Al[row * 64 + ((kk * 4 + quad) ^ (row & 7)) * 8];
            }
            #pragma unroll
            for (int i = 0; i < 4; ++i) {
                const int row = wn + i * 16 + l15;
                bfv[i] = *(const short8*)&Bl[row * 64 + ((kk * 4 + quad) ^ (row & 7)) * 8];
            }
            #pragma unroll
            for (int i = 0; i < 4; ++i)
                #pragma unroll
                for (int j = 0; j < 4; ++j)
                    acc[i][j] = __builtin_amdgcn_mfma_f32_16x16x32_bf16(
                        af[i], bfv[j], acc[i][j], 0, 0, 0);
        }
        __syncthreads();
    }

    #pragma unroll
    for (int i = 0; i < 4; ++i) {
        if (MODE == 0 && n0 >= 2048) {
            #pragma unroll
            for (int j = 0; j < 4; ++j) {        // V^T: pack 4 consecutive c
                const int mb = m0 + wm + i * 16 + quad * 4;
                const int n = n0 + wn + j * 16 + l15;
                const int b = mb >> 11, c0 = mb & 2047;
                const int nl = n & 1023, hh = nl >> 6, d = nl & 63;
                ushort4v pv;
                #pragma unroll
                for (int r = 0; r < 4; ++r) pv[r] = f2bf(acc[i][j][r]);
                *(ushort4v*)&obf[16777216 + ((size_t)(b * 16 + hh) * 64 + d) * 2048 + c0] = pv;
            }
        } else {
            #pragma unroll
            for (int r = 0; r < 4; ++r) {
                const int m = m0 + wm + i * 16 + quad * 4 + r;
                #pragma unroll
                for (int j = 0; j < 4; ++j) {
                    const int n = n0 + wn + j * 16 + l15;
                    const float v = acc[i][j][r];
                    if (MODE == 0) {   // Q,K: (B,H,C,D), z = n>>10
                        const int b = m >> 11, c = m & 2047;
                        const int z = n >> 10, nl = n & 1023, hh = nl >> 6, d = nl & 63;
                        obf[(size_t)z * 8388608 +
                            ((size_t)(b * 16 + hh) * 2048 + c) * 64 + d] = f2bf(v);
                    } else {
                        ofp[(size_t)m * 1024 + n] = v;
                    }
                }
            }
        }
    }
}

// ------ causal flash attention (transposed-S, paired tiles, LDS dbuf) -----
// Q(pre-scaled),K: (B,H,C,D) bf16; Vt: (B,H,D,C) bf16; Hid: (B,C,H*D) bf16.
// 512 thr = 8 waves, 16 q/wave -> 128 q per pass; block does q-tile xq and
// 15-xq (uniform 34 key-tiles). K/V double-buffered: stage(t+1) issued
// before compute(t); single barrier per tile. id&7 = bh&7 (XCD pinning).
__global__ __launch_bounds__(512) void attn_kernel(const unsigned short* __restrict__ Q,
                                                   const unsigned short* __restrict__ K,
                                                   const unsigned short* __restrict__ Vt,
                                                   unsigned short* __restrict__ Hid) {
    __shared__ __align__(16) unsigned short Kl[2][64 * 64];  // [buf][key][d]
    __shared__ __align__(16) unsigned short Vl[2][64 * 64];  // [buf][d][key]
    __shared__ __align__(16) unsigned short Pl[8][16 * 72];  // per-wave [q][k]
    const int id = blockIdx.x;
    const int bh = (id >> 6) * 8 + (id & 7);   // all xq of bh share id&7 (XCD)
    const int xq = (id >> 3) & 7;              // q-tile pair index 0..7
    const int b = bh >> 4, h = bh & 15;
    const int tid = threadIdx.x, w = tid >> 6, lane = tid & 63;
    const int quad = lane >> 4, l15 = lane & 15;
    const int sw = quad ^ (l15 & 7);
    const int srow = lane >> 3, sc = lane & 7;
    const int g8 = (sc ^ srow) * 8;            // staging source swizzle
    const int krow = w * 8 + srow;             // this lane's staged row
    const size_t bhs = (size_t)(b * 16 + h) * 2048 * 64;
    const unsigned short* Qb = Q + bhs;
    const unsigned short* Kb = K + bhs;
    const unsigned short* Vb = Vt + bhs;       // (D=64) x (C=2048)

    #pragma unroll
    for (int pass = 0; pass < 2; ++pass) {
        const int qt = pass ? (15 - xq) : xq;
        const int q0 = qt * 128;
        const int qw = q0 + w * 16;
        const int myq = qw + l15;
        const short8 bq0 = *(const short8*)&Qb[(size_t)myq * 64 + quad * 8];
        const short8 bq1 = *(const short8*)&Qb[(size_t)myq * 64 + 32 + quad * 8];

        floatx4 o[4];
        #pragma unroll
        for (int i = 0; i < 4; ++i) o[i] = (floatx4){0.f, 0.f, 0.f, 0.f};
        float li = 0.f;

        const int nT = (q0 + 128) >> 6;
        // protect buf0 from the previous pass's reads, then prologue stage
        __syncthreads();
        gl2lds16(&Kb[(size_t)krow * 64 + g8], &Kl[0][w * 512]);
        gl2lds16(&Vb[(size_t)krow * 2048 + g8], &Vl[0][w * 512]);

        for (int t = 0; t < nT; ++t) {
            const int k0 = t * 64;
            const int cb = t & 1;
            __syncthreads();   // buf[cb] staged (vmcnt drained pre-barrier)
            if (t + 1 < nT) {  // stage next tile into the other buffer
                const int kn = k0 + 64;
                gl2lds16(&Kb[(size_t)(kn + krow) * 64 + g8], &Kl[cb ^ 1][w * 512]);
                gl2lds16(&Vb[(size_t)krow * 2048 + kn + g8], &Vl[cb ^ 1][w * 512]);
            }
            if (k0 <= qw + 15) {
                // ---- S^T = K * Q^T (Q pre-scaled by 0.125*log2e) ----
                floatx4 s[4];
                #pragma unroll
                for (int kf = 0; kf < 4; ++kf) {
                    const int row = kf * 16 + l15;
                    const short8 ka0 = *(const short8*)&Kl[cb][row * 64 + sw * 8];
                    const short8 ka1 = *(const short8*)&Kl[cb][row * 64 + (sw ^ 4) * 8];
                    floatx4 ss = (floatx4){0.f, 0.f, 0.f, 0.f};
                    ss = __builtin_amdgcn_mfma_f32_16x16x32_bf16(ka0, bq0, ss, 0, 0, 0);
                    ss = __builtin_amdgcn_mfma_f32_16x16x32_bf16(ka1, bq1, ss, 0, 0, 0);
                    s[kf] = ss;
                }
                // ---- p = exp2(s) (raw v_exp_f32), mask only diagonal tile ----
                if (k0 + 63 > qw) {
                    #pragma unroll
                    for (int kf = 0; kf < 4; ++kf) {
                        ushort4v pw;
                        #pragma unroll
                        for (int r = 0; r < 4; ++r) {
                            const int key = k0 + kf * 16 + quad * 4 + r;
                            const float p = (key > myq) ? 0.f
                                            : __builtin_amdgcn_exp2f(s[kf][r]);
                            li += p;
                            pw[r] = f2bf(p);
                        }
                        *(ushort4v*)&Pl[w][l15 * 72 + kf * 16 + quad * 4] = pw;
                    }
                } else {
                    #pragma unroll
                    for (int kf = 0; kf < 4; ++kf) {
                        ushort4v pw;
                        #pragma unroll
                        for (int r = 0; r < 4; ++r) {
                            const float p = __builtin_amdgcn_exp2f(s[kf][r]);
                            li += p;
                            pw[r] = f2bf(p);
                        }
                        *(ushort4v*)&Pl[w][l15 * 72 + kf * 16 + quad * 4] = pw;
                    }
                }
                __threadfence_block();
                // ---- O^T += V^T * P^T (P-frags hoisted) ----
                const short8 pb0 = *(const short8*)&Pl[w][l15 * 72 + quad * 8];
                const short8 pb1 = *(const short8*)&Pl[w][l15 * 72 + 32 + quad * 8];
                #pragma unroll
                for (int nt = 0; nt < 4; ++nt) {
                    const int row = nt * 16 + l15;
                    const short8 va0 = *(const short8*)&Vl[cb][row * 64 + sw * 8];
                    const short8 va1 = *(const short8*)&Vl[cb][row * 64 + (sw ^ 4) * 8];
                    floatx4 oo = o[nt];
                    oo = __builtin_amdgcn_mfma_f32_16x16x32_bf16(va0, pb0, oo, 0, 0, 0);
                    oo = __builtin_amdgcn_mfma_f32_16x16x32_bf16(va1, pb1, oo, 0, 0, 0);
                    o[nt] = oo;
                }
            }
        }

        li += __shfl_xor(li, 16, 64);
        li += __shfl_xor(li, 32, 64);
        const float inv = 1.f / li;
        #pragma unroll
        for (int nt = 0; nt < 4; ++nt) {
            ushort4v ov;
            #pragma unroll
            for (int r = 0; r < 4; ++r) ov[r] = f2bf(o[nt][r] * inv);
            *(ushort4v*)&Hid[((size_t)b * 2048 + myq) * 1024 + h * 64 + nt * 16 + quad * 4] = ov;
        }
    }
}

extern "C" void kernel_launch(void* const* d_in, const int* in_sizes, int n_in,
                              void* d_out, int out_size, void* d_ws, size_t ws_size,
                              hipStream_t stream) {
    const float* x  = (const float*)d_in[0];
    const float* Wq = (const float*)d_in[1];
    const float* Wk = (const float*)d_in[2];
    const float* Wv = (const float*)d_in[3];
    const float* Wo = (const float*)d_in[4];
    float* out = (float*)d_out;
    unsigned short* ws = (unsigned short*)d_ws;

    const size_t XB  = 0;          // x bf16:           8192x1024
    const size_t WQT = 8388608;    // WqT,WkT,WvT,WoT:  4 x 1024x1024 (N x K)
    const size_t QO  = 12582912;   // Q,K (B,H,C,D) + V (B,H,D,C): 3 x 8192x1024
    const size_t HO  = 37748736;   // hidden (B,C,H*D): 8192x1024

    prep_kernel<<<9216, 256, 0, stream>>>(x, Wq, Wk, Wv, Wo, ws + XB, ws + WQT);

    // QKV: one GEMM, N=3072 (WqT|WkT|WvT contiguous), XCD-swizzled 1D grid
    gemm128<0, 24><<<1536, 256, 0, stream>>>(ws + XB, ws + WQT, ws + QO, nullptr);
    attn_kernel<<<512, 512, 0, stream>>>(ws + QO, ws + QO + 8388608,
                                         ws + QO + 16777216, ws + HO);
    gemm128<1, 8><<<512, 256, 0, stream>>>(ws + HO, ws + WQT + 3145728, nullptr, out);
}